// Round 7
// baseline (373.703 us; speedup 1.0000x reference)
//
#include <hip/hip_runtime.h>

namespace {

constexpr int B = 128, N = 2048, E = 32768;
constexpr int LOG2N = 11, LOG2E = 15;

// ws layout (bytes)
constexpr size_t OFF_P1 = 0;                          // layer1 partials: B*2*6*N*4 = 12 MB
constexpr size_t OFF_O2 = 12u * 1024 * 1024;          // layer2 node partials: 24 KB

__device__ __forceinline__ float hw_cos(float s)  { float d; asm("v_cos_f32 %0, %1" : "=v"(d) : "v"(s)); return d; }
__device__ __forceinline__ float hw_exp2(float s) { float d; asm("v_exp_f32 %0, %1" : "=v"(d) : "v"(s)); return d; }

// R11 edge-parallel layer, NO SORT. One block per (batch, half): 16384 raw
// edges, thread t handles edges {t, t+1024, ...} (coalesced 3-stream loads,
// depth-1 manual prefetch). Per record: full per-edge math + 2 ds_read_b128
// gathers + 6 ds_add_f32 into per-node planes (random dst -> few conflicts).
// R6 post-mortem: the segmented-scan machinery (44 cross-lane DS ops / 64
// edges) was the bottleneck (LDS pipe 3.6x oversubscribed vs VALU, VALUBusy
// 32%). Sortedness is not needed for correctness -> drop sort kernel + CSR
// round-trip entirely.
// MODE 0: lh = x[b]; writes all-node partials to part1[b][half][6][N].
// MODE 1: lh = h1 reconstructed from x + part1 (both halves); writes only
//         src/dst node partials to out2.
template <int MODE>
__global__ __launch_bounds__(1024, 4) void layerE_kernel(
    const float4* __restrict__ x, const int* __restrict__ edge_index,
    const float* __restrict__ edge_time, const float* __restrict__ timestamp,
    const float* __restrict__ part1, float* __restrict__ part1out,
    float* __restrict__ out2,
    const int* __restrict__ src_index, const int* __restrict__ dst_index,
    const float* __restrict__ tw, const float* __restrict__ tb,
    const float* __restrict__ Wq, const float* __restrict__ Wk,
    const float* __restrict__ Wv, const float* __restrict__ WoP,
    const float* __restrict__ boP) {
  __shared__ float4 lh[N];       // 32 KB
  __shared__ float  accS[6 * N]; // 48 KB
  int blk = blockIdx.x, b = blk >> 1, half = blk & 1, t = threadIdx.x;

  constexpr float INV2PI = 0.15915494309189535f;
  constexpr float QSCALE = 0.70710678118654752f * 1.4426950408889634f;  // rs2*log2e
  // uniform loads -> SGPRs (R6 evidence: VGPR_Count 32, SGPR 112)
  float twf2[4], tbf2[4], wqc[16], wkh[16], wkp[16], wvh[16], wvp[16];
#pragma unroll
  for (int j = 0; j < 4; j++) { twf2[j] = tw[j] * INV2PI; tbf2[j] = tb[j] * INV2PI; }
#pragma unroll
  for (int j = 0; j < 16; j++) wqc[j] = Wq[j] * QSCALE;
#pragma unroll
  for (int j = 0; j < 16; j++) { wkh[j] = Wk[j]; wkp[j] = Wk[16 + j]; }
#pragma unroll
  for (int j = 0; j < 16; j++) { wvh[j] = Wv[j]; wvp[j] = Wv[16 + j]; }

  // ---- prologue: fill lh ----
  if constexpr (MODE == 0) {
    const float4* hb = x + (((size_t)b) << LOG2N);
    lh[t] = hb[t];
    lh[t + 1024] = hb[t + 1024];
  } else {
    const float* p1 = part1 + ((size_t)(b * 2)) * 6 * N;
#pragma unroll
    for (int nn = 0; nn < 2; ++nn) {
      int n = t + nn * 1024;
      float sarr[6];
#pragma unroll
      for (int j = 0; j < 6; j++) sarr[j] = p1[j * N + n] + p1[6 * N + j * N + n];
      float den0 = (sarr[0] == 0.f) ? 1.f : sarr[0];
      float den1 = (sarr[1] == 0.f) ? 1.f : sarr[1];
      float at0 = sarr[2] / den0, at1 = sarr[3] / den0;
      float at2 = sarr[4] / den1, at3 = sarr[5] / den1;
      float4 xb = x[(((size_t)b) << LOG2N) + n];
      float o0 = boP[0] + at0 * WoP[0] + at1 * WoP[4] + at2 * WoP[8]  + at3 * WoP[12];
      float o1 = boP[1] + at0 * WoP[1] + at1 * WoP[5] + at2 * WoP[9]  + at3 * WoP[13];
      float o2 = boP[2] + at0 * WoP[2] + at1 * WoP[6] + at2 * WoP[10] + at3 * WoP[14];
      float o3 = boP[3] + at0 * WoP[3] + at1 * WoP[7] + at2 * WoP[11] + at3 * WoP[15];
      lh[n] = make_float4(fmaxf(xb.x + o0, 0.f), fmaxf(xb.y + o1, 0.f),
                          fmaxf(xb.z + o2, 0.f), fmaxf(xb.w + o3, 0.f));
    }
  }
  // zero accumulators (12288 floats = 3072 float4)
  {
    float4* a4 = (float4*)accS;
    float4 z = make_float4(0.f, 0.f, 0.f, 0.f);
    a4[t] = z; a4[t + 1024] = z; a4[t + 2048] = z;
  }
  __syncthreads();

  // ---- edge loop: 16 coalesced windows, depth-1 prefetch ----
  const int* __restrict__ srcp = edge_index + (((size_t)(2 * b)) << LOG2E) + half * (E / 2);
  const int* __restrict__ dstp = edge_index + (((size_t)(2 * b + 1)) << LOG2E) + half * (E / 2);
  const float* __restrict__ etp = edge_time + (((size_t)b) << LOG2E) + half * (E / 2);
  float ts = timestamp[b];

  int sC = srcp[t], dC = dstp[t];
  float eC = etp[t];
#pragma unroll
  for (int k = 0; k < 16; ++k) {
    int sN = 0, dN = 0; float eN = 0.f;
    if (k < 15) {
      int idx = (k + 1) * 1024 + t;
      sN = srcp[idx]; dN = dstp[idx]; eN = etp[idx];
    }
    float4 hs = lh[sC];
    float4 hd = lh[dC];
    float dt = ts - eC;

    float ph0 = hw_cos(dt * twf2[0] + tbf2[0]);
    float ph1 = hw_cos(dt * twf2[1] + tbf2[1]);
    float ph2 = hw_cos(dt * twf2[2] + tbf2[2]);
    float ph3 = hw_cos(dt * twf2[3] + tbf2[3]);

    float q0 = hd.x * wqc[0] + hd.y * wqc[4] + hd.z * wqc[8]  + hd.w * wqc[12];
    float q1 = hd.x * wqc[1] + hd.y * wqc[5] + hd.z * wqc[9]  + hd.w * wqc[13];
    float q2 = hd.x * wqc[2] + hd.y * wqc[6] + hd.z * wqc[10] + hd.w * wqc[14];
    float q3 = hd.x * wqc[3] + hd.y * wqc[7] + hd.z * wqc[11] + hd.w * wqc[15];

    float k0 = hs.x * wkh[0] + hs.y * wkh[4] + hs.z * wkh[8]  + hs.w * wkh[12]
             + ph0 * wkp[0] + ph1 * wkp[4] + ph2 * wkp[8]  + ph3 * wkp[12];
    float k1 = hs.x * wkh[1] + hs.y * wkh[5] + hs.z * wkh[9]  + hs.w * wkh[13]
             + ph0 * wkp[1] + ph1 * wkp[5] + ph2 * wkp[9]  + ph3 * wkp[13];
    float k2 = hs.x * wkh[2] + hs.y * wkh[6] + hs.z * wkh[10] + hs.w * wkh[14]
             + ph0 * wkp[2] + ph1 * wkp[6] + ph2 * wkp[10] + ph3 * wkp[14];
    float k3 = hs.x * wkh[3] + hs.y * wkh[7] + hs.z * wkh[11] + hs.w * wkh[15]
             + ph0 * wkp[3] + ph1 * wkp[7] + ph2 * wkp[11] + ph3 * wkp[15];

    float p0 = hw_exp2(q0 * k0 + q1 * k1);
    float p1 = hw_exp2(q2 * k2 + q3 * k3);

    float v0 = hs.x * wvh[0] + hs.y * wvh[4] + hs.z * wvh[8]  + hs.w * wvh[12]
             + ph0 * wvp[0] + ph1 * wvp[4] + ph2 * wvp[8]  + ph3 * wvp[12];
    float v1 = hs.x * wvh[1] + hs.y * wvh[5] + hs.z * wvh[9]  + hs.w * wvh[13]
             + ph0 * wvp[1] + ph1 * wvp[5] + ph2 * wvp[9]  + ph3 * wvp[13];
    float v2 = hs.x * wvh[2] + hs.y * wvh[6] + hs.z * wvh[10] + hs.w * wvh[14]
             + ph0 * wvp[2] + ph1 * wvp[6] + ph2 * wvp[10] + ph3 * wvp[14];
    float v3 = hs.x * wvh[3] + hs.y * wvh[7] + hs.z * wvh[11] + hs.w * wvh[15]
             + ph0 * wvp[3] + ph1 * wvp[7] + ph2 * wvp[11] + ph3 * wvp[15];

    atomicAdd(&accS[0 * N + dC], p0);
    atomicAdd(&accS[1 * N + dC], p1);
    atomicAdd(&accS[2 * N + dC], p0 * v0);
    atomicAdd(&accS[3 * N + dC], p0 * v1);
    atomicAdd(&accS[4 * N + dC], p1 * v2);
    atomicAdd(&accS[5 * N + dC], p1 * v3);

    sC = sN; dC = dN; eC = eN;
  }

  __syncthreads();

  // ---- epilogue ----
  if constexpr (MODE == 0) {
    float4* po = (float4*)(part1out + ((size_t)(b * 2 + half)) * 6 * N);
    const float4* a4 = (const float4*)accS;
    po[t] = a4[t]; po[t + 1024] = a4[t + 1024]; po[t + 2048] = a4[t + 2048];
  } else {
    if (t < 12) {
      int slot = t / 6, j = t % 6;
      int node = (slot == 0) ? src_index[b] : dst_index[b];
      out2[(((size_t)(b * 2 + half)) * 2 + slot) * 6 + j] = accS[j * N + node];
    }
  }
}

// Final: reconstruct h1 (x + part1, layer0 Wo/bo) and h2 (h1 + out2, layer1
// Wo/bo) for just the src/dst nodes, then the linear head. (R6-validated.)
__global__ void final_kernel(const float4* __restrict__ x,
                             const float* __restrict__ part1,
                             const float* __restrict__ out2,
                             const int* __restrict__ src_index, const int* __restrict__ dst_index,
                             const float* __restrict__ timestamp,
                             const float* __restrict__ tw, const float* __restrict__ tb,
                             const float* __restrict__ Wo, const float* __restrict__ bo,
                             const float* __restrict__ W_lin, const float* __restrict__ b_lin,
                             float* __restrict__ out) {
  int b = threadIdx.x;
  if (b >= B) return;
  int nodes[2] = { src_index[b], dst_index[b] };
  float ts = timestamp[b];
  const float* p1 = part1 + ((size_t)(b * 2)) * 6 * N;
  float h2v[2][4];
#pragma unroll
  for (int slot = 0; slot < 2; ++slot) {
    int n = nodes[slot];
    float sarr[6];
#pragma unroll
    for (int j = 0; j < 6; j++) sarr[j] = p1[j * N + n] + p1[6 * N + j * N + n];
    float den0 = (sarr[0] == 0.f) ? 1.f : sarr[0];
    float den1 = (sarr[1] == 0.f) ? 1.f : sarr[1];
    float at0 = sarr[2] / den0, at1 = sarr[3] / den0;
    float at2 = sarr[4] / den1, at3 = sarr[5] / den1;
    float4 xb = x[(((size_t)b) << LOG2N) + n];
    float h10 = fmaxf(xb.x + bo[0] + at0 * Wo[0] + at1 * Wo[4] + at2 * Wo[8]  + at3 * Wo[12], 0.f);
    float h11 = fmaxf(xb.y + bo[1] + at0 * Wo[1] + at1 * Wo[5] + at2 * Wo[9]  + at3 * Wo[13], 0.f);
    float h12 = fmaxf(xb.z + bo[2] + at0 * Wo[2] + at1 * Wo[6] + at2 * Wo[10] + at3 * Wo[14], 0.f);
    float h13 = fmaxf(xb.w + bo[3] + at0 * Wo[3] + at1 * Wo[7] + at2 * Wo[11] + at3 * Wo[15], 0.f);
    float t2[6];
#pragma unroll
    for (int j = 0; j < 6; j++)
      t2[j] = out2[(((size_t)(b * 2 + 0)) * 2 + slot) * 6 + j]
            + out2[(((size_t)(b * 2 + 1)) * 2 + slot) * 6 + j];
    float d20 = (t2[0] == 0.f) ? 1.f : t2[0];
    float d21 = (t2[1] == 0.f) ? 1.f : t2[1];
    float b0 = t2[2] / d20, b1 = t2[3] / d20, b2 = t2[4] / d21, b3 = t2[5] / d21;
    const float* Wo1 = Wo + 16; const float* bo1 = bo + 4;
    h2v[slot][0] = fmaxf(h10 + bo1[0] + b0 * Wo1[0] + b1 * Wo1[4] + b2 * Wo1[8]  + b3 * Wo1[12], 0.f);
    h2v[slot][1] = fmaxf(h11 + bo1[1] + b0 * Wo1[1] + b1 * Wo1[5] + b2 * Wo1[9]  + b3 * Wo1[13], 0.f);
    h2v[slot][2] = fmaxf(h12 + bo1[2] + b0 * Wo1[2] + b1 * Wo1[6] + b2 * Wo1[10] + b3 * Wo1[14], 0.f);
    h2v[slot][3] = fmaxf(h13 + bo1[3] + b0 * Wo1[3] + b1 * Wo1[7] + b2 * Wo1[11] + b3 * Wo1[15], 0.f);
  }
  float f[12];
#pragma unroll
  for (int j = 0; j < 4; j++) { f[j] = h2v[0][j]; f[4 + j] = h2v[1][j]; }
#pragma unroll
  for (int j = 0; j < 4; j++) f[8 + j] = __cosf(ts * tw[j] + tb[j]);
#pragma unroll
  for (int c = 0; c < 2; c++) {
    float o = b_lin[c];
#pragma unroll
    for (int j = 0; j < 12; j++) o += f[j] * W_lin[j * 2 + c];
    out[b * 2 + c] = o;
  }
}

}  // namespace

extern "C" void kernel_launch(void* const* d_in, const int* in_sizes, int n_in,
                              void* d_out, int out_size, void* d_ws, size_t ws_size,
                              hipStream_t stream) {
  (void)in_sizes; (void)n_in; (void)out_size; (void)ws_size;
  const float* x         = (const float*)d_in[0];
  const int*   edge_idx  = (const int*)d_in[1];
  const float* edge_time = (const float*)d_in[2];
  const float* timestamp = (const float*)d_in[3];
  const int*   src_index = (const int*)d_in[4];
  const int*   dst_index = (const int*)d_in[5];
  const float* time_w    = (const float*)d_in[6];
  const float* time_b    = (const float*)d_in[7];
  const float* Wq        = (const float*)d_in[8];
  const float* Wk        = (const float*)d_in[9];
  const float* Wv        = (const float*)d_in[10];
  const float* Wo        = (const float*)d_in[11];
  const float* bo        = (const float*)d_in[12];
  const float* W_lin     = (const float*)d_in[13];
  const float* b_lin     = (const float*)d_in[14];

  char* ws = (char*)d_ws;
  float* part1 = (float*)(ws + OFF_P1);
  float* out2  = (float*)(ws + OFF_O2);

  layerE_kernel<0><<<2 * B, 1024, 0, stream>>>(
      (const float4*)x, edge_idx, edge_time, timestamp, nullptr, part1, nullptr,
      src_index, dst_index, time_w, time_b,
      Wq + 0, Wk + 0, Wv + 0, nullptr, nullptr);

  layerE_kernel<1><<<2 * B, 1024, 0, stream>>>(
      (const float4*)x, edge_idx, edge_time, timestamp, part1, nullptr, out2,
      src_index, dst_index, time_w, time_b,
      Wq + 16, Wk + 32, Wv + 32, Wo + 0, bo + 0);

  final_kernel<<<1, 128, 0, stream>>>(
      (const float4*)x, part1, out2, src_index, dst_index, timestamp,
      time_w, time_b, Wo, bo, W_lin, b_lin, (float*)d_out);
}